// Round 6
// baseline (292.053 us; speedup 1.0000x reference)
//
#include <hip/hip_runtime.h>

#define EPS 1e-6f

using bfrag = __attribute__((ext_vector_type(8))) short;     // 8 x 16-bit
using hfrag = __attribute__((ext_vector_type(8))) _Float16;  // 8 f16
using ffrag = __attribute__((ext_vector_type(4))) float;     // C/D frag
typedef unsigned short ushortT;

#define MFMA(a, b, c) __builtin_amdgcn_mfma_f32_16x16x32_bf16((a), (b), (c), 0, 0, 0)
#define MFMA16(a, b, c) __builtin_amdgcn_mfma_f32_16x16x32_f16((a), (b), (c), 0, 0, 0)

__device__ __forceinline__ ushortT bf_hi(float x) {
  unsigned u = __builtin_bit_cast(unsigned, x);
  return (ushortT)((u + 0x7FFFu + ((u >> 16) & 1u)) >> 16);
}
__device__ __forceinline__ float uaf(unsigned u) { return __builtin_bit_cast(float, u); }
// HW packed f32x2 -> bf16x2 (RTNE): D[15:0]=bf16(a), D[31:16]=bf16(b)
__device__ __forceinline__ unsigned cvtpk(float a, float b) {
  unsigned d;
  asm("v_cvt_pk_bf16_f32 %0, %1, %2" : "=v"(d) : "v"(a), "v"(b));
  return d;
}
// HW packed f32x2 -> f16x2 (RTZ): D[15:0]=f16(a), D[31:16]=f16(b)
__device__ __forceinline__ unsigned pkf16(float a, float b) {
  unsigned d;
  asm("v_cvt_pkrtz_f16_f32 %0, %1, %2" : "=v"(d) : "v"(a), "v"(b));
  return d;
}
__device__ __forceinline__ int op_of(int k) { return (k < 4) ? k : ((k >> 1) + 2); }

// ---------------------------------------------------------------------------
// ws layout: Gp 0..256K | W1p 256K..384K | W2p 384K..448K | cbias 448K+
// Mixed dtype: G slots 0..5 + W1p k 0..5 are f16; G slots 6,7 + W1p k 6,7 and
// W2p are bf16-hi. Packed B-fragment order for W[K x N]:
//   elem j of lane L = W[kk*32 + (L>>4)*8 + j][nt*16 + (L&15)]
// ---------------------------------------------------------------------------
__global__ void prologue(const float* __restrict__ ops_W1,
                         const float* __restrict__ ops_W2,
                         const float* __restrict__ ops_b2,
                         const float* __restrict__ pres_W1,
                         const float* __restrict__ pres_b1,
                         const float* __restrict__ pres_W2,
                         const float* __restrict__ pres_b2,
                         const float* __restrict__ fus_W1,
                         const float* __restrict__ fus_b1,
                         const float* __restrict__ fus_W2,
                         ushortT* __restrict__ Gp,
                         ushortT* __restrict__ W1p,
                         ushortT* __restrict__ W2p,
                         float* __restrict__ cb) {
  const int blk = blockIdx.x;
  const int tid = threadIdx.x;

  if (blk < 512) {
    // ---- pack G: Gp row r (slot-ordered hidden) <- k = KMAP[r>>6]
    int r = blk, n = tid;
    int slot = r >> 6;
    const int KMAP[8] = {0, 2, 3, 4, 1, 5, 6, 7};
    int k = KMAP[slot];
    int op = op_of(k);
    const float* w2 = ops_W2 + (size_t)(op * 64 + (r & 63)) * 128;
    const float* w1 = fus_W1 + (size_t)(k * 128) * 256 + n;
    float a0 = 0.f, a1 = 0.f, a2 = 0.f, a3 = 0.f;
#pragma unroll 8
    for (int d = 0; d < 128; d += 4) {
      a0 = fmaf(w2[d], w1[(size_t)d * 256], a0);
      a1 = fmaf(w2[d + 1], w1[(size_t)(d + 1) * 256], a1);
      a2 = fmaf(w2[d + 2], w1[(size_t)(d + 2) * 256], a2);
      a3 = fmaf(w2[d + 3], w1[(size_t)(d + 3) * 256], a3);
    }
    float acc = (a0 + a1) + (a2 + a3);
    ushortT outv;
    if (slot < 6) {
      _Float16 hv = (_Float16)acc;
      outv = __builtin_bit_cast(ushortT, hv);
    } else {
      outv = bf_hi(acc);
    }
    int nt = n >> 4, kk = r >> 5, quad = (r >> 3) & 3, j = r & 7;
    int lane = quad * 16 + (n & 15);
    Gp[((nt * 16 + kk) * 64 + lane) * 8 + j] = outv;
  } else if (blk < 544) {
    // ---- pack ops_W1: [k 8][nt 4][kk 4][lane 64][j 8]   (k = ORIGINAL k index)
    int gid = (blk - 512) * 256 + tid;
    int lane = gid & 63, kk = (gid >> 6) & 3, nt = (gid >> 8) & 3, k = gid >> 10;
    int op = op_of(k);
    int col = nt * 16 + (lane & 15);
#pragma unroll
    for (int j = 0; j < 8; ++j) {
      int d = kk * 32 + ((lane >> 4) & 3) * 8 + j;
      float w = ops_W1[((size_t)op * 128 + d) * 64 + col];
      ushortT outv;
      if (k < 6) {
        _Float16 hv = (_Float16)w;
        outv = __builtin_bit_cast(ushortT, hv);
      } else {
        outv = bf_hi(w);
      }
      W1p[gid * 8 + j] = outv;
    }
  } else if (blk < 560) {
    // ---- pack fus_W2: [nt 8][kk 8][lane 64][j 8]  (bf16-hi)
    int gid = (blk - 544) * 256 + tid;
    int lane = gid & 63, kk = (gid >> 6) & 7, nt = gid >> 9;
    int col = nt * 16 + (lane & 15);
#pragma unroll
    for (int j = 0; j < 8; ++j) {
      int d = kk * 32 + ((lane >> 4) & 3) * 8 + j;
      W2p[gid * 8 + j] = bf_hi(fus_W2[(size_t)d * 128 + col]);
    }
  } else {
    // ---- cbias[c][n]
    int c = blk - 560, n = tid;
    __shared__ float hrelu[64];
    __shared__ float ptok[128];
    if (n < 64) hrelu[n] = fmaxf(pres_W1[c * 64 + n] + pres_b1[n], 0.f);
    __syncthreads();
    if (n < 128) {
      float p0 = pres_b2[n], p1 = 0.f;
#pragma unroll 8
      for (int hh = 0; hh < 64; hh += 2) {
        p0 = fmaf(hrelu[hh], pres_W2[hh * 128 + n], p0);
        p1 = fmaf(hrelu[hh + 1], pres_W2[(hh + 1) * 128 + n], p1);
      }
      ptok[n] = p0 + p1;
    }
    __syncthreads();
    float acc = fus_b1[n];
#pragma unroll 4
    for (int d = 0; d < 128; ++d)
      acc = fmaf(ptok[d], fus_W1[(size_t)(1024 + d) * 256 + n], acc);
    float acc2 = 0.f;  // ops_b2 fold (zeros in setup, kept for generality)
    for (int k = 0; k < 8; ++k) {
      int op = op_of(k);
#pragma unroll 4
      for (int d = 0; d < 128; ++d)
        acc2 = fmaf(ops_b2[op * 128 + d], fus_W1[(size_t)(k * 128 + d) * 256 + n], acc2);
    }
    cb[c * 256 + n] = acc + acc2;
  }
}

// ---------------------------------------------------------------------------
// Main: 32 tokens/block (two 16-row M-tiles), 256 threads = 4 waves.
// ROUND-BASED schedule (empirically best: R2=114us vs merged R3/R4=145/130).
// Wave wv handles tile (wv&1) and feature role (wv>>1) of each round's pair.
// Rounds 0-2 (bounded features): f16 single-fragment path.
// Round 3 (ratio features k6,k7, ~1e7 range): bf16 hi+lo path.
// Round k-order: r0:(0,2) r1:(3,4) r2:(1,5) r3:(6,7)  [G packed to match]
// k2 = scalar*(k0 frags); k3 = |A-B| direct; k5 = relu(-s4+b4), no MFMA.
// LDS strides padded for bank spread: H 136->140 (70 dwords, %32=6),
// D 264->268 (134 dwords, %32=6). Old stride-4 aliasing caused ~8-way
// conflicts on p3 ds_read_b128 and b16 H-stores (5.66M conflict cycles).
// ---------------------------------------------------------------------------
__device__ __forceinline__ void ldX(const float* Xrow, int quad, float (&r)[32]) {
#pragma unroll
  for (int kk = 0; kk < 4; ++kk) {
    float4 t0 = *(const float4*)(Xrow + kk * 32 + quad * 8);
    float4 t1 = *(const float4*)(Xrow + kk * 32 + quad * 8 + 4);
    r[kk * 8 + 0] = t0.x; r[kk * 8 + 1] = t0.y; r[kk * 8 + 2] = t0.z; r[kk * 8 + 3] = t0.w;
    r[kk * 8 + 4] = t1.x; r[kk * 8 + 5] = t1.y; r[kk * 8 + 6] = t1.z; r[kk * 8 + 7] = t1.w;
  }
}

struct Frag2 {
  bfrag h[4];
  bfrag l[4];
};

union U4 {
  unsigned u[4];
  bfrag b;
};

#define FM_MUL 0
#define FM_ADD 1
#define FM_SUB 2
#define FM_ABS 3
#define FM_DAB 4
#define FM_DBA 5

#define HH_LD 140
#define HL_LD 140
#define DH_LD 268

// ---- f16 single-fragment builder (bounded features only) ----
template <int M>
__device__ __forceinline__ void buildFragsF16(const float (&af)[32], const float (&bf)[32],
                                              bfrag (&h)[4]) {
#pragma unroll
  for (int kk = 0; kk < 4; ++kk) {
    U4 uh;
#pragma unroll
    for (int p = 0; p < 4; ++p) {
      float a0 = af[kk * 8 + 2 * p],     b0 = bf[kk * 8 + 2 * p];
      float a1 = af[kk * 8 + 2 * p + 1], b1 = bf[kk * 8 + 2 * p + 1];
      float f0, f1;
      if constexpr (M == FM_MUL)      { f0 = a0 * b0; f1 = a1 * b1; }
      else if constexpr (M == FM_ADD) { f0 = a0 + b0; f1 = a1 + b1; }
      else if constexpr (M == FM_SUB) { f0 = a0 - b0; f1 = a1 - b1; }
      else                            { f0 = fabsf(a0 - b0); f1 = fabsf(a1 - b1); }
      uh.u[p] = pkf16(f0, f1);
    }
    h[kk] = uh.b;
  }
}

// ---- bf16 hi+lo builder (ratio features) ----
template <int M>
__device__ __forceinline__ void buildFrags(const float (&af)[32], const float (&bf)[32],
                                           Frag2& fr) {
#pragma unroll
  for (int kk = 0; kk < 4; ++kk) {
    U4 uh, ul;
#pragma unroll
    for (int p = 0; p < 4; ++p) {
      float a0 = af[kk * 8 + 2 * p],     b0 = bf[kk * 8 + 2 * p];
      float a1 = af[kk * 8 + 2 * p + 1], b1 = bf[kk * 8 + 2 * p + 1];
      float f0, f1;
      if constexpr (M == FM_DAB) {
        f0 = a0 * __builtin_amdgcn_rcpf(b0 + EPS);
        f1 = a1 * __builtin_amdgcn_rcpf(b1 + EPS);
      } else {
        f0 = b0 * __builtin_amdgcn_rcpf(a0 + EPS);
        f1 = b1 * __builtin_amdgcn_rcpf(a1 + EPS);
      }
      unsigned dh = cvtpk(f0, f1);
      float r0 = f0 - uaf(dh << 16);
      float r1 = f1 - uaf(dh & 0xFFFF0000u);
      uh.u[p] = dh;
      ul.u[p] = cvtpk(r0, r1);
    }
    fr.h[kk] = uh.b;
    fr.l[kk] = ul.b;
  }
}

// one k-feature against ALL 4 nt blocks of W1 (N=64), f16 single: 16 MFMA
template <int K>
__device__ __forceinline__ void mmAllF16(const bfrag (&h)[4], int lane,
                                         const ushortT* __restrict__ W1p, ffrag (&s)[4]) {
#pragma unroll
  for (int nt = 0; nt < 4; ++nt) {
    const ushortT* wp = W1p + ((K * 4 + nt) * 4) * 512 + lane * 8;
    ffrag acc = {0.f, 0.f, 0.f, 0.f};
#pragma unroll
    for (int kk = 0; kk < 4; ++kk) {
      hfrag w = __builtin_bit_cast(hfrag, *(const bfrag*)(wp + kk * 512));
      acc = MFMA16(__builtin_bit_cast(hfrag, h[kk]), w, acc);
    }
    s[nt] = acc;
  }
}

// bf16 hi+lo variant: 32 MFMA
template <int K>
__device__ __forceinline__ void mmAll(const Frag2& fr, int lane,
                                      const ushortT* __restrict__ W1p, ffrag (&s)[4]) {
#pragma unroll
  for (int nt = 0; nt < 4; ++nt) {
    const ushortT* wp = W1p + ((K * 4 + nt) * 4) * 512 + lane * 8;
    ffrag acc = {0.f, 0.f, 0.f, 0.f};
#pragma unroll
    for (int kk = 0; kk < 4; ++kk) {
      bfrag w = *(const bfrag*)(wp + kk * 512);
      acc = MFMA(fr.h[kk], w, acc);
      acc = MFMA(fr.l[kk], w, acc);
    }
    s[nt] = acc;
  }
}

__device__ __forceinline__ void ldBias(const float* __restrict__ ops_b1, int OP, int c0,
                                       float (&bb)[4]) {
#pragma unroll
  for (int nt = 0; nt < 4; ++nt) bb[nt] = ops_b1[OP * 64 + nt * 16 + c0];
}

// f16 H store: relu(scl*s+bias) -> Hh plane only (packed cvt)
__device__ __forceinline__ void storeHf(ffrag s, float scl, float bias, int rbase, int col,
                                        ushortT (*Hh)[HH_LD]) {
  float v[4];
#pragma unroll
  for (int i = 0; i < 4; ++i) v[i] = fmaxf(fmaf(s[i], scl, bias), 0.f);
#pragma unroll
  for (int p = 0; p < 2; ++p) {
    unsigned d = pkf16(v[2 * p], v[2 * p + 1]);
    Hh[rbase + 2 * p][col] = (ushortT)(d & 0xFFFFu);
    Hh[rbase + 2 * p + 1][col] = (ushortT)(d >> 16);
  }
}

__device__ __forceinline__ void storeHf4(const ffrag (&s)[4], float scl, const float (&bb)[4],
                                         int rbase, int colbase, int c0,
                                         ushortT (*Hh)[HH_LD]) {
#pragma unroll
  for (int nt = 0; nt < 4; ++nt)
    storeHf(s[nt], scl, bb[nt], rbase, colbase + nt * 16 + c0, Hh);
}

// bf16 hi+lo H store (ratio features)
__device__ __forceinline__ void storeH(ffrag s, float bias, int rbase, int col,
                                       ushortT (*Hh)[HH_LD], ushortT (*Hl)[HL_LD]) {
  float v[4];
#pragma unroll
  for (int i = 0; i < 4; ++i) v[i] = fmaxf(s[i] + bias, 0.f);
#pragma unroll
  for (int p = 0; p < 2; ++p) {
    unsigned dh = cvtpk(v[2 * p], v[2 * p + 1]);
    float r0 = v[2 * p] - uaf(dh << 16);
    float r1 = v[2 * p + 1] - uaf(dh & 0xFFFF0000u);
    unsigned dl = cvtpk(r0, r1);
    Hh[rbase + 2 * p][col] = (ushortT)(dh & 0xFFFFu);
    Hh[rbase + 2 * p + 1][col] = (ushortT)(dh >> 16);
    Hl[rbase + 2 * p][col] = (ushortT)(dl & 0xFFFFu);
    Hl[rbase + 2 * p + 1][col] = (ushortT)(dl >> 16);
  }
}

__device__ __forceinline__ void storeH4(const ffrag (&s)[4], const float (&bb)[4],
                                        int rbase, int colbase, int c0,
                                        ushortT (*Hh)[HH_LD], ushortT (*Hl)[HL_LD]) {
#pragma unroll
  for (int nt = 0; nt < 4; ++nt)
    storeH(s[nt], bb[nt], rbase, colbase + nt * 16 + c0, Hh, Hl);
}

// p3 f16 rounds 0-2: H single plane, G f16: 32 MFMA/wave
__device__ __forceinline__ void p3roundF16(int r, int wv, int lane, int quad, int c0,
                                           ushortT (*Hh)[HH_LD],
                                           const ushortT* __restrict__ Gp,
                                           ffrag (&u)[4], ffrag (&v)[4]) {
#pragma unroll
  for (int kk = 0; kk < 4; ++kk) {
    hfrag ah0 = __builtin_bit_cast(hfrag, *(const bfrag*)&Hh[c0][kk * 32 + quad * 8]);
    hfrag ah1 = __builtin_bit_cast(hfrag, *(const bfrag*)&Hh[16 + c0][kk * 32 + quad * 8]);
#pragma unroll
    for (int nt4 = 0; nt4 < 4; ++nt4) {
      hfrag g = __builtin_bit_cast(
          hfrag, *(const bfrag*)(Gp + (((wv * 4 + nt4) * 16 + r * 4 + kk) * 64 + lane) * 8));
      u[nt4] = MFMA16(ah0, g, u[nt4]);
      v[nt4] = MFMA16(ah1, g, v[nt4]);
    }
  }
}

// p3 bf16 hi+lo (round 3): 64 MFMA/wave
__device__ __forceinline__ void p3round(int r, int wv, int lane, int quad, int c0,
                                        ushortT (*Hh)[HH_LD], ushortT (*Hl)[HL_LD],
                                        const ushortT* __restrict__ Gp,
                                        ffrag (&u)[4], ffrag (&v)[4]) {
#pragma unroll
  for (int kk = 0; kk < 4; ++kk) {
    bfrag ah0 = *(const bfrag*)&Hh[c0][kk * 32 + quad * 8];
    bfrag al0 = *(const bfrag*)&Hl[c0][kk * 32 + quad * 8];
    bfrag ah1 = *(const bfrag*)&Hh[16 + c0][kk * 32 + quad * 8];
    bfrag al1 = *(const bfrag*)&Hl[16 + c0][kk * 32 + quad * 8];
#pragma unroll
    for (int nt4 = 0; nt4 < 4; ++nt4) {
      bfrag g = *(const bfrag*)(Gp + (((wv * 4 + nt4) * 16 + r * 4 + kk) * 64 + lane) * 8);
      u[nt4] = MFMA(ah0, g, u[nt4]);
      u[nt4] = MFMA(al0, g, u[nt4]);
      v[nt4] = MFMA(ah1, g, v[nt4]);
      v[nt4] = MFMA(al1, g, v[nt4]);
    }
  }
}

__global__ __launch_bounds__(256, 3)
void drel_main(const float* __restrict__ x, const int* __restrict__ presence,
               const int* __restrict__ idx_i, const int* __restrict__ idx_j,
               const float* __restrict__ ops_b1, const float* __restrict__ fus_b2,
               const ushortT* __restrict__ W1p, const ushortT* __restrict__ Gp,
               const ushortT* __restrict__ W2p, const float* __restrict__ cbias,
               float* __restrict__ out) {
  __shared__ __align__(16) char smem[51840];
  float   (*Xs)[132]   = reinterpret_cast<float(*)[132]>(smem);               // 33792 B
  ushortT (*Hh)[HH_LD] = reinterpret_cast<ushortT(*)[HH_LD]>(smem + 33792);   //  8960 B
  ushortT (*Hl)[HL_LD] = reinterpret_cast<ushortT(*)[HL_LD]>(smem + 42752);   //  8960 B
  ushortT (*Dh)[DH_LD] = reinterpret_cast<ushortT(*)[DH_LD]>(smem + 33792);   // aliases H (17152 B)
  int* sCombo = reinterpret_cast<int*>(smem + 51712);                         //   128 B

  const int tid = threadIdx.x;
  const int wv = tid >> 6, lane = tid & 63, quad = lane >> 4, c0 = lane & 15;
  const int wtile = wv & 1;    // which 16-token tile this wave builds
  const int wrole = wv >> 1;   // feature-set role

  const int blk = blockIdx.x;
  const int b = blk / 63;
  const int p0 = (blk % 63) * 32;

  // ---- stage x[b] (64 rows x 128 f32) into LDS, fully coalesced ----
  const float* xb = x + (size_t)b * 64 * 128;
#pragma unroll
  for (int it = 0; it < 8; ++it) {
    int i = tid + it * 256;
    int row = i >> 5, c4 = (i & 31) * 4;
    *(float4*)&Xs[row][c4] = *(const float4*)(xb + row * 128 + c4);
  }
  if (tid < 32) {
    int p = p0 + tid;
    int pa = presence[b * 64 + idx_i[p]];
    int pb = presence[b * 64 + idx_j[p]];
    sCombo[tid] = pa ? (pb ? 0 : 1) : (pb ? 2 : 3);
  }

  // token rows for THIS wave's tile (lane serves token c0 of tile wtile)
  const int rI = idx_i[p0 + wtile * 16 + c0];
  const int rJ = idx_j[p0 + wtile * 16 + c0];
  const int rbase = wtile * 16 + quad * 4;

  // ---- phase 3 accumulators (persist across all 4 rounds) ----
  ffrag u[4], v[4];
  __syncthreads();   // X + sCombo ready
  {
    int comb0[4], comb1[4];
#pragma unroll
    for (int i = 0; i < 4; ++i) {
      comb0[i] = sCombo[quad * 4 + i];
      comb1[i] = sCombo[16 + quad * 4 + i];
    }
#pragma unroll
    for (int nt4 = 0; nt4 < 4; ++nt4) {
      int col = (wv * 4 + nt4) * 16 + c0;
#pragma unroll
      for (int i = 0; i < 4; ++i) {
        u[nt4][i] = cbias[comb0[i] * 256 + col];
        v[nt4][i] = cbias[comb1[i] * 256 + col];
      }
    }
  }

  float af[32], bf[32];
  bfrag fh[4];   // f16 fragments
  ffrag s4[4];   // k4 pre-bias accumulators (role-1 waves), reused for k5 in round 2

  // ---- round 0: k0 (role 0), k2 = scalar*(k0 frags) (role 1) — f16 ----
  {
    ldX(Xs[rI], quad, af); ldX(Xs[rJ], quad, bf);
    buildFragsF16<FM_MUL>(af, bf, fh);
    ffrag s[4];
    float bb[4];
    if (wrole == 0) {
      ldBias(ops_b1, 0, c0, bb);
      mmAllF16<0>(fh, lane, W1p, s);
      storeHf4(s, 1.f, bb, rbase, 0, c0, Hh);
    } else {
      float sa = 0.f, sb = 0.f;
#pragma unroll
      for (int q = 0; q < 32; ++q) { sa = fmaf(af[q], af[q], sa); sb = fmaf(bf[q], bf[q], sb); }
      sa += __shfl_xor(sa, 16); sb += __shfl_xor(sb, 16);
      sa += __shfl_xor(sa, 32); sb += __shfl_xor(sb, 32);
      float scl = (1.f / (sqrtf(sa) + EPS)) * (1.f / (sqrtf(sb) + EPS));
      ldBias(ops_b1, 2, c0, bb);
      mmAllF16<2>(fh, lane, W1p, s);
      storeHf4(s, scl, bb, rbase, 64, c0, Hh);
    }
  }
  __syncthreads();
  p3roundF16(0, wv, lane, quad, c0, Hh, Gp, u, v);
  __syncthreads();

  // ---- round 1: k3 = |A-B| (role 0), k4 = A-B (role 1, save s4) — f16 ----
  {
    ldX(Xs[rI], quad, af); ldX(Xs[rJ], quad, bf);
    float bb[4];
    if (wrole == 0) {
      buildFragsF16<FM_ABS>(af, bf, fh);
      ffrag s[4];
      ldBias(ops_b1, 3, c0, bb);
      mmAllF16<3>(fh, lane, W1p, s);
      storeHf4(s, 1.f, bb, rbase, 0, c0, Hh);
    } else {
      buildFragsF16<FM_SUB>(af, bf, fh);
      ldBias(ops_b1, 4, c0, bb);
      mmAllF16<4>(fh, lane, W1p, s4);
      storeHf4(s4, 1.f, bb, rbase, 64, c0, Hh);
    }
  }
  __syncthreads();
  p3roundF16(1, wv, lane, quad, c0, Hh, Gp, u, v);
  __syncthreads();

  // ---- round 2: k1 = A+B (role 0), k5 = relu(-s4 + b4) (role 1, no MFMA) — f16 ----
  {
    float bb[4];
    if (wrole == 0) {
      ldX(Xs[rI], quad, af); ldX(Xs[rJ], quad, bf);
      buildFragsF16<FM_ADD>(af, bf, fh);
      ffrag s[4];
      ldBias(ops_b1, 1, c0, bb);
      mmAllF16<1>(fh, lane, W1p, s);
      storeHf4(s, 1.f, bb, rbase, 0, c0, Hh);
    } else {
      ldBias(ops_b1, 4, c0, bb);
      storeHf4(s4, -1.f, bb, rbase, 64, c0, Hh);
    }
  }
  __syncthreads();
  p3roundF16(2, wv, lane, quad, c0, Hh, Gp, u, v);
  __syncthreads();

  // ---- round 3: k6 (role 0), k7 (role 1) — bf16 hi+lo (1e7 range) ----
  {
    ldX(Xs[rI], quad, af); ldX(Xs[rJ], quad, bf);
    Frag2 fr;
    ffrag s[4];
    float bb[4];
    ldBias(ops_b1, 5, c0, bb);
    if (wrole == 0) {
      buildFrags<FM_DAB>(af, bf, fr);
      mmAll<6>(fr, lane, W1p, s);
      storeH4(s, bb, rbase, 0, c0, Hh, Hl);
    } else {
      buildFrags<FM_DBA>(af, bf, fr);
      mmAll<7>(fr, lane, W1p, s);
      storeH4(s, bb, rbase, 64, c0, Hh, Hl);
    }
  }
  __syncthreads();
  p3round(3, wv, lane, quad, c0, Hh, Hl, Gp, u, v);
  __syncthreads();   // H fully consumed -> D may alias

  // ---- write Hid (relu, bf16-hi via packed cvt) into D ----
#pragma unroll
  for (int nt4 = 0; nt4 < 4; ++nt4) {
    int col = (wv * 4 + nt4) * 16 + c0;
#pragma unroll
    for (int p = 0; p < 2; ++p) {
      unsigned du = cvtpk(fmaxf(u[nt4][2 * p], 0.f), fmaxf(u[nt4][2 * p + 1], 0.f));
      Dh[quad * 4 + 2 * p][col] = (ushortT)(du & 0xFFFFu);
      Dh[quad * 4 + 2 * p + 1][col] = (ushortT)(du >> 16);
      unsigned dv = cvtpk(fmaxf(v[nt4][2 * p], 0.f), fmaxf(v[nt4][2 * p + 1], 0.f));
      Dh[16 + quad * 4 + 2 * p][col] = (ushortT)(dv & 0xFFFFu);
      Dh[16 + quad * 4 + 2 * p + 1][col] = (ushortT)(dv >> 16);
    }
  }
  __syncthreads();

  // ---- phase 4: out = Hid @ fus_W2 + fus_b2 (bf16-hi) ----
  ffrag o[2], q[2];
#pragma unroll
  for (int nt2 = 0; nt2 < 2; ++nt2) {
    float bias = fus_b2[(wv * 2 + nt2) * 16 + c0];
    o[nt2] = ffrag{bias, bias, bias, bias};
    q[nt2] = o[nt2];
  }
#pragma unroll
  for (int kk = 0; kk < 8; ++kk) {
    bfrag dh0 = *(const bfrag*)&Dh[c0][kk * 32 + quad * 8];
    bfrag dh1 = *(const bfrag*)&Dh[16 + c0][kk * 32 + quad * 8];
#pragma unroll
    for (int nt2 = 0; nt2 < 2; ++nt2) {
      bfrag w = *(const bfrag*)(W2p + (((wv * 2 + nt2) * 8 + kk) * 64 + lane) * 8);
      o[nt2] = MFMA(dh0, w, o[nt2]);
      q[nt2] = MFMA(dh1, w, q[nt2]);
    }
  }
#pragma unroll
  for (int nt2 = 0; nt2 < 2; ++nt2) {
    int col = (wv * 2 + nt2) * 16 + c0;
#pragma unroll
    for (int i = 0; i < 4; ++i) {
      int row = quad * 4 + i;
      out[(size_t)(b * 2016 + p0 + row) * 128 + col] = o[nt2][i];
      out[(size_t)(b * 2016 + p0 + 16 + row) * 128 + col] = q[nt2][i];
    }
  }
}

// ---------------------------------------------------------------------------
extern "C" void kernel_launch(void* const* d_in, const int* in_sizes, int n_in,
                              void* d_out, int out_size, void* d_ws, size_t ws_size,
                              hipStream_t stream) {
  const float* x        = (const float*)d_in[0];
  const int*   presence = (const int*)d_in[1];
  const int*   idx_i    = (const int*)d_in[2];
  const int*   idx_j    = (const int*)d_in[3];
  const float* ops_W1   = (const float*)d_in[4];
  const float* ops_b1   = (const float*)d_in[5];
  const float* ops_W2   = (const float*)d_in[6];
  const float* ops_b2   = (const float*)d_in[7];
  const float* pres_W1  = (const float*)d_in[8];
  const float* pres_b1  = (const float*)d_in[9];
  const float* pres_W2  = (const float*)d_in[10];
  const float* pres_b2  = (const float*)d_in[11];
  const float* fus_W1   = (const float*)d_in[12];
  const float* fus_b1   = (const float*)d_in[13];
  const float* fus_W2   = (const float*)d_in[14];
  const float* fus_b2   = (const float*)d_in[15];

  char* ws = (char*)d_ws;
  ushortT* Gp  = (ushortT*)(ws);            // 512*256*2   = 262144 B
  ushortT* W1p = (ushortT*)(ws + 262144);   // 8*4*4*512*2 = 131072 B
  ushortT* W2p = (ushortT*)(ws + 393216);   // 8*8*512*2   =  65536 B
  float*   CB  = (float*)(ws + 458752);     // 4*256*4     =   4096 B

  prologue<<<564, 256, 0, stream>>>(ops_W1, ops_W2, ops_b2, pres_W1, pres_b1,
                                    pres_W2, pres_b2, fus_W1, fus_b1, fus_W2,
                                    Gp, W1p, W2p, CB);
  // 64 batches * 63 blocks, 32 tokens each = 129024 tokens
  drel_main<<<4032, 256, 0, stream>>>(x, presence, idx_i, idx_j, ops_b1, fus_b2,
                                      W1p, Gp, W2p, CB, (float*)d_out);
}

// Round 7
// 241.204 us; speedup vs baseline: 1.2108x; 1.2108x over previous
//
#include <hip/hip_runtime.h>

#define EPS 1e-6f

using bfrag = __attribute__((ext_vector_type(8))) short;     // 8 x 16-bit
using hfrag = __attribute__((ext_vector_type(8))) _Float16;  // 8 f16
using ffrag = __attribute__((ext_vector_type(4))) float;     // C/D frag
typedef unsigned short ushortT;

#define MFMA(a, b, c) __builtin_amdgcn_mfma_f32_16x16x32_bf16((a), (b), (c), 0, 0, 0)
#define MFMA16(a, b, c) __builtin_amdgcn_mfma_f32_16x16x32_f16((a), (b), (c), 0, 0, 0)

__device__ __forceinline__ ushortT bf_hi(float x) {
  unsigned u = __builtin_bit_cast(unsigned, x);
  return (ushortT)((u + 0x7FFFu + ((u >> 16) & 1u)) >> 16);
}
__device__ __forceinline__ float uaf(unsigned u) { return __builtin_bit_cast(float, u); }
// HW packed f32x2 -> bf16x2 (RTNE): D[15:0]=bf16(a), D[31:16]=bf16(b)
__device__ __forceinline__ unsigned cvtpk(float a, float b) {
  unsigned d;
  asm("v_cvt_pk_bf16_f32 %0, %1, %2" : "=v"(d) : "v"(a), "v"(b));
  return d;
}
// HW packed f32x2 -> f16x2 (RTZ): D[15:0]=f16(a), D[31:16]=f16(b)
__device__ __forceinline__ unsigned pkf16(float a, float b) {
  unsigned d;
  asm("v_cvt_pkrtz_f16_f32 %0, %1, %2" : "=v"(d) : "v"(a), "v"(b));
  return d;
}
__device__ __forceinline__ int op_of(int k) { return (k < 4) ? k : ((k >> 1) + 2); }

// ---------------------------------------------------------------------------
// ws layout: Gp 0..256K | W1p 256K..384K | W2p 384K..448K | cbias 448K+
// Mixed dtype: G slots 0..5 + W1p k 0..5 are f16; G slots 6,7 + W1p k 6,7 and
// W2p are bf16-hi. Packed B-fragment order for W[K x N]:
//   elem j of lane L = W[kk*32 + (L>>4)*8 + j][nt*16 + (L&15)]
// ---------------------------------------------------------------------------
__global__ void prologue(const float* __restrict__ ops_W1,
                         const float* __restrict__ ops_W2,
                         const float* __restrict__ ops_b2,
                         const float* __restrict__ pres_W1,
                         const float* __restrict__ pres_b1,
                         const float* __restrict__ pres_W2,
                         const float* __restrict__ pres_b2,
                         const float* __restrict__ fus_W1,
                         const float* __restrict__ fus_b1,
                         const float* __restrict__ fus_W2,
                         ushortT* __restrict__ Gp,
                         ushortT* __restrict__ W1p,
                         ushortT* __restrict__ W2p,
                         float* __restrict__ cb) {
  const int blk = blockIdx.x;
  const int tid = threadIdx.x;

  if (blk < 512) {
    // ---- pack G: Gp row r (slot-ordered hidden) <- k = KMAP[r>>6]
    int r = blk, n = tid;
    int slot = r >> 6;
    const int KMAP[8] = {0, 2, 3, 4, 1, 5, 6, 7};
    int k = KMAP[slot];
    int op = op_of(k);
    const float* w2 = ops_W2 + (size_t)(op * 64 + (r & 63)) * 128;
    const float* w1 = fus_W1 + (size_t)(k * 128) * 256 + n;
    float a0 = 0.f, a1 = 0.f, a2 = 0.f, a3 = 0.f;
#pragma unroll 8
    for (int d = 0; d < 128; d += 4) {
      a0 = fmaf(w2[d], w1[(size_t)d * 256], a0);
      a1 = fmaf(w2[d + 1], w1[(size_t)(d + 1) * 256], a1);
      a2 = fmaf(w2[d + 2], w1[(size_t)(d + 2) * 256], a2);
      a3 = fmaf(w2[d + 3], w1[(size_t)(d + 3) * 256], a3);
    }
    float acc = (a0 + a1) + (a2 + a3);
    ushortT outv;
    if (slot < 6) {
      _Float16 hv = (_Float16)acc;
      outv = __builtin_bit_cast(ushortT, hv);
    } else {
      outv = bf_hi(acc);
    }
    int nt = n >> 4, kk = r >> 5, quad = (r >> 3) & 3, j = r & 7;
    int lane = quad * 16 + (n & 15);
    Gp[((nt * 16 + kk) * 64 + lane) * 8 + j] = outv;
  } else if (blk < 544) {
    // ---- pack ops_W1: [k 8][nt 4][kk 4][lane 64][j 8]   (k = ORIGINAL k index)
    int gid = (blk - 512) * 256 + tid;
    int lane = gid & 63, kk = (gid >> 6) & 3, nt = (gid >> 8) & 3, k = gid >> 10;
    int op = op_of(k);
    int col = nt * 16 + (lane & 15);
#pragma unroll
    for (int j = 0; j < 8; ++j) {
      int d = kk * 32 + ((lane >> 4) & 3) * 8 + j;
      float w = ops_W1[((size_t)op * 128 + d) * 64 + col];
      ushortT outv;
      if (k < 6) {
        _Float16 hv = (_Float16)w;
        outv = __builtin_bit_cast(ushortT, hv);
      } else {
        outv = bf_hi(w);
      }
      W1p[gid * 8 + j] = outv;
    }
  } else if (blk < 560) {
    // ---- pack fus_W2: [nt 8][kk 8][lane 64][j 8]  (bf16-hi)
    int gid = (blk - 544) * 256 + tid;
    int lane = gid & 63, kk = (gid >> 6) & 7, nt = gid >> 9;
    int col = nt * 16 + (lane & 15);
#pragma unroll
    for (int j = 0; j < 8; ++j) {
      int d = kk * 32 + ((lane >> 4) & 3) * 8 + j;
      W2p[gid * 8 + j] = bf_hi(fus_W2[(size_t)d * 128 + col]);
    }
  } else {
    // ---- cbias[c][n]
    int c = blk - 560, n = tid;
    __shared__ float hrelu[64];
    __shared__ float ptok[128];
    if (n < 64) hrelu[n] = fmaxf(pres_W1[c * 64 + n] + pres_b1[n], 0.f);
    __syncthreads();
    if (n < 128) {
      float p0 = pres_b2[n], p1 = 0.f;
#pragma unroll 8
      for (int hh = 0; hh < 64; hh += 2) {
        p0 = fmaf(hrelu[hh], pres_W2[hh * 128 + n], p0);
        p1 = fmaf(hrelu[hh + 1], pres_W2[(hh + 1) * 128 + n], p1);
      }
      ptok[n] = p0 + p1;
    }
    __syncthreads();
    float acc = fus_b1[n];
#pragma unroll 4
    for (int d = 0; d < 128; ++d)
      acc = fmaf(ptok[d], fus_W1[(size_t)(1024 + d) * 256 + n], acc);
    float acc2 = 0.f;  // ops_b2 fold (zeros in setup, kept for generality)
    for (int k = 0; k < 8; ++k) {
      int op = op_of(k);
#pragma unroll 4
      for (int d = 0; d < 128; ++d)
        acc2 = fmaf(ops_b2[op * 128 + d], fus_W1[(size_t)(k * 128 + d) * 256 + n], acc2);
    }
    cb[c * 256 + n] = acc + acc2;
  }
}

// ---------------------------------------------------------------------------
// Main: 32 tokens/block (two 16-row M-tiles), 256 threads = 4 waves.
// ROUND-BASED schedule; LDS strides 136/264 (16B-aligned rows -> ds_read_b128;
// the 140-pad variant broke alignment and regressed 114->166us).
// Wave wv handles tile (wv&1) and feature role (wv>>1) of each round's pair.
// Rounds 0-2 (bounded features): f16 single-fragment path.
// Round 3 (ratio features k6,k7, ~1e7 range): bf16 hi+lo path.
// Round k-order: r0:(0,2) r1:(3,4) r2:(1,5) r3:(6,7)  [G packed to match]
// NEW: G-operand preload (16 frags/round, 64 VGPR) + W1 double-buffer in p2 —
// exploits VGPR headroom (old kernel: 84 used vs ~168 budget at 3 waves/SIMD)
// to hide ~200cy L2 latency that serialized each kk-step.
// ---------------------------------------------------------------------------
__device__ __forceinline__ void ldX(const float* Xrow, int quad, float (&r)[32]) {
#pragma unroll
  for (int kk = 0; kk < 4; ++kk) {
    float4 t0 = *(const float4*)(Xrow + kk * 32 + quad * 8);
    float4 t1 = *(const float4*)(Xrow + kk * 32 + quad * 8 + 4);
    r[kk * 8 + 0] = t0.x; r[kk * 8 + 1] = t0.y; r[kk * 8 + 2] = t0.z; r[kk * 8 + 3] = t0.w;
    r[kk * 8 + 4] = t1.x; r[kk * 8 + 5] = t1.y; r[kk * 8 + 6] = t1.z; r[kk * 8 + 7] = t1.w;
  }
}

struct Frag2 {
  bfrag h[4];
  bfrag l[4];
};

union U4 {
  unsigned u[4];
  bfrag b;
};

#define FM_MUL 0
#define FM_ADD 1
#define FM_SUB 2
#define FM_ABS 3
#define FM_DAB 4
#define FM_DBA 5

// ---- f16 single-fragment builder (bounded features only) ----
template <int M>
__device__ __forceinline__ void buildFragsF16(const float (&af)[32], const float (&bf)[32],
                                              bfrag (&h)[4]) {
#pragma unroll
  for (int kk = 0; kk < 4; ++kk) {
    U4 uh;
#pragma unroll
    for (int p = 0; p < 4; ++p) {
      float a0 = af[kk * 8 + 2 * p],     b0 = bf[kk * 8 + 2 * p];
      float a1 = af[kk * 8 + 2 * p + 1], b1 = bf[kk * 8 + 2 * p + 1];
      float f0, f1;
      if constexpr (M == FM_MUL)      { f0 = a0 * b0; f1 = a1 * b1; }
      else if constexpr (M == FM_ADD) { f0 = a0 + b0; f1 = a1 + b1; }
      else if constexpr (M == FM_SUB) { f0 = a0 - b0; f1 = a1 - b1; }
      else                            { f0 = fabsf(a0 - b0); f1 = fabsf(a1 - b1); }
      uh.u[p] = pkf16(f0, f1);
    }
    h[kk] = uh.b;
  }
}

// ---- bf16 hi+lo builder (ratio features) ----
template <int M>
__device__ __forceinline__ void buildFrags(const float (&af)[32], const float (&bf)[32],
                                           Frag2& fr) {
#pragma unroll
  for (int kk = 0; kk < 4; ++kk) {
    U4 uh, ul;
#pragma unroll
    for (int p = 0; p < 4; ++p) {
      float a0 = af[kk * 8 + 2 * p],     b0 = bf[kk * 8 + 2 * p];
      float a1 = af[kk * 8 + 2 * p + 1], b1 = bf[kk * 8 + 2 * p + 1];
      float f0, f1;
      if constexpr (M == FM_DAB) {
        f0 = a0 * __builtin_amdgcn_rcpf(b0 + EPS);
        f1 = a1 * __builtin_amdgcn_rcpf(b1 + EPS);
      } else {
        f0 = b0 * __builtin_amdgcn_rcpf(a0 + EPS);
        f1 = b1 * __builtin_amdgcn_rcpf(a1 + EPS);
      }
      unsigned dh = cvtpk(f0, f1);
      float r0 = f0 - uaf(dh << 16);
      float r1 = f1 - uaf(dh & 0xFFFF0000u);
      uh.u[p] = dh;
      ul.u[p] = cvtpk(r0, r1);
    }
    fr.h[kk] = uh.b;
    fr.l[kk] = ul.b;
  }
}

// one k-feature against ALL 4 nt blocks of W1 (N=64), f16 single: 16 MFMA.
// W fragments double-buffered: prefetch nt+1 while nt's MFMAs run.
template <int K>
__device__ __forceinline__ void mmAllF16(const bfrag (&h)[4], int lane,
                                         const ushortT* __restrict__ W1p, ffrag (&s)[4]) {
  const ushortT* wp = W1p + (K * 16) * 512 + lane * 8;
  bfrag wa[4], wb[4];
#pragma unroll
  for (int kk = 0; kk < 4; ++kk) wa[kk] = *(const bfrag*)(wp + kk * 512);
#pragma unroll
  for (int nt = 0; nt < 4; ++nt) {
    if (nt < 3) {
      bfrag (&wn)[4] = (nt & 1) ? wa : wb;
#pragma unroll
      for (int kk = 0; kk < 4; ++kk)
        wn[kk] = *(const bfrag*)(wp + (nt + 1) * 2048 + kk * 512);
    }
    const bfrag (&wc)[4] = (nt & 1) ? wb : wa;
    ffrag acc = {0.f, 0.f, 0.f, 0.f};
#pragma unroll
    for (int kk = 0; kk < 4; ++kk)
      acc = MFMA16(__builtin_bit_cast(hfrag, h[kk]), __builtin_bit_cast(hfrag, wc[kk]), acc);
    s[nt] = acc;
  }
}

// bf16 hi+lo variant: 32 MFMA, same double-buffer
template <int K>
__device__ __forceinline__ void mmAll(const Frag2& fr, int lane,
                                      const ushortT* __restrict__ W1p, ffrag (&s)[4]) {
  const ushortT* wp = W1p + (K * 16) * 512 + lane * 8;
  bfrag wa[4], wb[4];
#pragma unroll
  for (int kk = 0; kk < 4; ++kk) wa[kk] = *(const bfrag*)(wp + kk * 512);
#pragma unroll
  for (int nt = 0; nt < 4; ++nt) {
    if (nt < 3) {
      bfrag (&wn)[4] = (nt & 1) ? wa : wb;
#pragma unroll
      for (int kk = 0; kk < 4; ++kk)
        wn[kk] = *(const bfrag*)(wp + (nt + 1) * 2048 + kk * 512);
    }
    const bfrag (&wc)[4] = (nt & 1) ? wb : wa;
    ffrag acc = {0.f, 0.f, 0.f, 0.f};
#pragma unroll
    for (int kk = 0; kk < 4; ++kk) {
      acc = MFMA(fr.h[kk], wc[kk], acc);
      acc = MFMA(fr.l[kk], wc[kk], acc);
    }
    s[nt] = acc;
  }
}

__device__ __forceinline__ void ldBias(const float* __restrict__ ops_b1, int OP, int c0,
                                       float (&bb)[4]) {
#pragma unroll
  for (int nt = 0; nt < 4; ++nt) bb[nt] = ops_b1[OP * 64 + nt * 16 + c0];
}

// f16 H store: relu(scl*s+bias) -> Hh plane only (packed cvt)
__device__ __forceinline__ void storeHf(ffrag s, float scl, float bias, int rbase, int col,
                                        ushortT (*Hh)[136]) {
  float v[4];
#pragma unroll
  for (int i = 0; i < 4; ++i) v[i] = fmaxf(fmaf(s[i], scl, bias), 0.f);
#pragma unroll
  for (int p = 0; p < 2; ++p) {
    unsigned d = pkf16(v[2 * p], v[2 * p + 1]);
    Hh[rbase + 2 * p][col] = (ushortT)(d & 0xFFFFu);
    Hh[rbase + 2 * p + 1][col] = (ushortT)(d >> 16);
  }
}

__device__ __forceinline__ void storeHf4(const ffrag (&s)[4], float scl, const float (&bb)[4],
                                         int rbase, int colbase, int c0,
                                         ushortT (*Hh)[136]) {
#pragma unroll
  for (int nt = 0; nt < 4; ++nt)
    storeHf(s[nt], scl, bb[nt], rbase, colbase + nt * 16 + c0, Hh);
}

// bf16 hi+lo H store (ratio features)
__device__ __forceinline__ void storeH(ffrag s, float bias, int rbase, int col,
                                       ushortT (*Hh)[136], ushortT (*Hl)[136]) {
  float v[4];
#pragma unroll
  for (int i = 0; i < 4; ++i) v[i] = fmaxf(s[i] + bias, 0.f);
#pragma unroll
  for (int p = 0; p < 2; ++p) {
    unsigned dh = cvtpk(v[2 * p], v[2 * p + 1]);
    float r0 = v[2 * p] - uaf(dh << 16);
    float r1 = v[2 * p + 1] - uaf(dh & 0xFFFF0000u);
    unsigned dl = cvtpk(r0, r1);
    Hh[rbase + 2 * p][col] = (ushortT)(dh & 0xFFFFu);
    Hh[rbase + 2 * p + 1][col] = (ushortT)(dh >> 16);
    Hl[rbase + 2 * p][col] = (ushortT)(dl & 0xFFFFu);
    Hl[rbase + 2 * p + 1][col] = (ushortT)(dl >> 16);
  }
}

__device__ __forceinline__ void storeH4(const ffrag (&s)[4], const float (&bb)[4],
                                        int rbase, int colbase, int c0,
                                        ushortT (*Hh)[136], ushortT (*Hl)[136]) {
#pragma unroll
  for (int nt = 0; nt < 4; ++nt)
    storeH(s[nt], bb[nt], rbase, colbase + nt * 16 + c0, Hh, Hl);
}

// p3 f16 rounds 0-2: preload all 16 G frags (global), then ds_read + MFMA.
__device__ __forceinline__ void p3roundF16(int r, int wv, int lane, int quad, int c0,
                                           ushortT (*Hh)[136],
                                           const ushortT* __restrict__ Gp,
                                           ffrag (&u)[4], ffrag (&v)[4]) {
  bfrag g[4][4];
  const ushortT* gp = Gp + ((wv * 64 + r * 4) * 64 + lane) * 8;
#pragma unroll
  for (int nt4 = 0; nt4 < 4; ++nt4)
#pragma unroll
    for (int kk = 0; kk < 4; ++kk)
      g[nt4][kk] = *(const bfrag*)(gp + nt4 * 8192 + kk * 512);
#pragma unroll
  for (int kk = 0; kk < 4; ++kk) {
    hfrag ah0 = __builtin_bit_cast(hfrag, *(const bfrag*)&Hh[c0][kk * 32 + quad * 8]);
    hfrag ah1 = __builtin_bit_cast(hfrag, *(const bfrag*)&Hh[16 + c0][kk * 32 + quad * 8]);
#pragma unroll
    for (int nt4 = 0; nt4 < 4; ++nt4) {
      u[nt4] = MFMA16(ah0, __builtin_bit_cast(hfrag, g[nt4][kk]), u[nt4]);
      v[nt4] = MFMA16(ah1, __builtin_bit_cast(hfrag, g[nt4][kk]), v[nt4]);
    }
  }
}

// p3 bf16 hi+lo (round 3): preload 16 G frags, 64 MFMA/wave
__device__ __forceinline__ void p3round(int r, int wv, int lane, int quad, int c0,
                                        ushortT (*Hh)[136], ushortT (*Hl)[136],
                                        const ushortT* __restrict__ Gp,
                                        ffrag (&u)[4], ffrag (&v)[4]) {
  bfrag g[4][4];
  const ushortT* gp = Gp + ((wv * 64 + r * 4) * 64 + lane) * 8;
#pragma unroll
  for (int nt4 = 0; nt4 < 4; ++nt4)
#pragma unroll
    for (int kk = 0; kk < 4; ++kk)
      g[nt4][kk] = *(const bfrag*)(gp + nt4 * 8192 + kk * 512);
#pragma unroll
  for (int kk = 0; kk < 4; ++kk) {
    bfrag ah0 = *(const bfrag*)&Hh[c0][kk * 32 + quad * 8];
    bfrag al0 = *(const bfrag*)&Hl[c0][kk * 32 + quad * 8];
    bfrag ah1 = *(const bfrag*)&Hh[16 + c0][kk * 32 + quad * 8];
    bfrag al1 = *(const bfrag*)&Hl[16 + c0][kk * 32 + quad * 8];
#pragma unroll
    for (int nt4 = 0; nt4 < 4; ++nt4) {
      u[nt4] = MFMA(ah0, g[nt4][kk], u[nt4]);
      u[nt4] = MFMA(al0, g[nt4][kk], u[nt4]);
      v[nt4] = MFMA(ah1, g[nt4][kk], v[nt4]);
      v[nt4] = MFMA(al1, g[nt4][kk], v[nt4]);
    }
  }
}

__global__ __launch_bounds__(256, 3)
void drel_main(const float* __restrict__ x, const int* __restrict__ presence,
               const int* __restrict__ idx_i, const int* __restrict__ idx_j,
               const float* __restrict__ ops_b1, const float* __restrict__ fus_b2,
               const ushortT* __restrict__ W1p, const ushortT* __restrict__ Gp,
               const ushortT* __restrict__ W2p, const float* __restrict__ cbias,
               float* __restrict__ out) {
  __shared__ __align__(16) char smem[51328];
  float   (*Xs)[132]  = reinterpret_cast<float(*)[132]>(smem);            // 33792 B
  ushortT (*Hh)[136]  = reinterpret_cast<ushortT(*)[136]>(smem + 33792);  //  8704 B
  ushortT (*Hl)[136]  = reinterpret_cast<ushortT(*)[136]>(smem + 42496);  //  8704 B
  ushortT (*Dh)[264]  = reinterpret_cast<ushortT(*)[264]>(smem + 33792);  // aliases H
  int* sCombo = reinterpret_cast<int*>(smem + 51200);

  const int tid = threadIdx.x;
  const int wv = tid >> 6, lane = tid & 63, quad = lane >> 4, c0 = lane & 15;
  const int wtile = wv & 1;    // which 16-token tile this wave builds
  const int wrole = wv >> 1;   // feature-set role

  const int blk = blockIdx.x;
  const int b = blk / 63;
  const int p0 = (blk % 63) * 32;

  // ---- stage x[b] (64 rows x 128 f32) into LDS, fully coalesced ----
  const float* xb = x + (size_t)b * 64 * 128;
#pragma unroll
  for (int it = 0; it < 8; ++it) {
    int i = tid + it * 256;
    int row = i >> 5, c4 = (i & 31) * 4;
    *(float4*)&Xs[row][c4] = *(const float4*)(xb + row * 128 + c4);
  }
  if (tid < 32) {
    int p = p0 + tid;
    int pa = presence[b * 64 + idx_i[p]];
    int pb = presence[b * 64 + idx_j[p]];
    sCombo[tid] = pa ? (pb ? 0 : 1) : (pb ? 2 : 3);
  }

  // token rows for THIS wave's tile (lane serves token c0 of tile wtile)
  const int rI = idx_i[p0 + wtile * 16 + c0];
  const int rJ = idx_j[p0 + wtile * 16 + c0];
  const int rbase = wtile * 16 + quad * 4;

  // ---- phase 3 accumulators (persist across all 4 rounds) ----
  ffrag u[4], v[4];
  __syncthreads();   // X + sCombo ready
  {
    int comb0[4], comb1[4];
#pragma unroll
    for (int i = 0; i < 4; ++i) {
      comb0[i] = sCombo[quad * 4 + i];
      comb1[i] = sCombo[16 + quad * 4 + i];
    }
#pragma unroll
    for (int nt4 = 0; nt4 < 4; ++nt4) {
      int col = (wv * 4 + nt4) * 16 + c0;
#pragma unroll
      for (int i = 0; i < 4; ++i) {
        u[nt4][i] = cbias[comb0[i] * 256 + col];
        v[nt4][i] = cbias[comb1[i] * 256 + col];
      }
    }
  }

  float af[32], bf[32];
  bfrag fh[4];   // f16 fragments
  ffrag s4[4];   // k4 pre-bias accumulators (role-1 waves), reused for k5 in round 2

  // ---- round 0: k0 (role 0), k2 = scalar*(k0 frags) (role 1) — f16 ----
  {
    ldX(Xs[rI], quad, af); ldX(Xs[rJ], quad, bf);
    buildFragsF16<FM_MUL>(af, bf, fh);
    ffrag s[4];
    float bb[4];
    if (wrole == 0) {
      ldBias(ops_b1, 0, c0, bb);
      mmAllF16<0>(fh, lane, W1p, s);
      storeHf4(s, 1.f, bb, rbase, 0, c0, Hh);
    } else {
      float sa = 0.f, sb = 0.f;
#pragma unroll
      for (int q = 0; q < 32; ++q) { sa = fmaf(af[q], af[q], sa); sb = fmaf(bf[q], bf[q], sb); }
      sa += __shfl_xor(sa, 16); sb += __shfl_xor(sb, 16);
      sa += __shfl_xor(sa, 32); sb += __shfl_xor(sb, 32);
      float scl = (1.f / (sqrtf(sa) + EPS)) * (1.f / (sqrtf(sb) + EPS));
      ldBias(ops_b1, 2, c0, bb);
      mmAllF16<2>(fh, lane, W1p, s);
      storeHf4(s, scl, bb, rbase, 64, c0, Hh);
    }
  }
  __syncthreads();
  p3roundF16(0, wv, lane, quad, c0, Hh, Gp, u, v);
  __syncthreads();

  // ---- round 1: k3 = |A-B| (role 0), k4 = A-B (role 1, save s4) — f16 ----
  {
    ldX(Xs[rI], quad, af); ldX(Xs[rJ], quad, bf);
    float bb[4];
    if (wrole == 0) {
      buildFragsF16<FM_ABS>(af, bf, fh);
      ffrag s[4];
      ldBias(ops_b1, 3, c0, bb);
      mmAllF16<3>(fh, lane, W1p, s);
      storeHf4(s, 1.f, bb, rbase, 0, c0, Hh);
    } else {
      buildFragsF16<FM_SUB>(af, bf, fh);
      ldBias(ops_b1, 4, c0, bb);
      mmAllF16<4>(fh, lane, W1p, s4);
      storeHf4(s4, 1.f, bb, rbase, 64, c0, Hh);
    }
  }
  __syncthreads();
  p3roundF16(1, wv, lane, quad, c0, Hh, Gp, u, v);
  __syncthreads();

  // ---- round 2: k1 = A+B (role 0), k5 = relu(-s4 + b4) (role 1, no MFMA) — f16 ----
  {
    float bb[4];
    if (wrole == 0) {
      ldX(Xs[rI], quad, af); ldX(Xs[rJ], quad, bf);
      buildFragsF16<FM_ADD>(af, bf, fh);
      ffrag s[4];
      ldBias(ops_b1, 1, c0, bb);
      mmAllF16<1>(fh, lane, W1p, s);
      storeHf4(s, 1.f, bb, rbase, 0, c0, Hh);
    } else {
      ldBias(ops_b1, 4, c0, bb);
      storeHf4(s4, -1.f, bb, rbase, 64, c0, Hh);
    }
  }
  __syncthreads();
  p3roundF16(2, wv, lane, quad, c0, Hh, Gp, u, v);
  __syncthreads();

  // ---- round 3: k6 (role 0), k7 (role 1) — bf16 hi+lo (1e7 range) ----
  {
    ldX(Xs[rI], quad, af); ldX(Xs[rJ], quad, bf);
    Frag2 fr;
    ffrag s[4];
    float bb[4];
    ldBias(ops_b1, 5, c0, bb);
    if (wrole == 0) {
      buildFrags<FM_DAB>(af, bf, fr);
      mmAll<6>(fr, lane, W1p, s);
      storeH4(s, bb, rbase, 0, c0, Hh, Hl);
    } else {
      buildFrags<FM_DBA>(af, bf, fr);
      mmAll<7>(fr, lane, W1p, s);
      storeH4(s, bb, rbase, 64, c0, Hh, Hl);
    }
  }
  __syncthreads();
  p3round(3, wv, lane, quad, c0, Hh, Hl, Gp, u, v);
  __syncthreads();   // H fully consumed -> D may alias

  // ---- write Hid (relu, bf16-hi via packed cvt) into D ----
#pragma unroll
  for (int nt4 = 0; nt4 < 4; ++nt4) {
    int col = (wv * 4 + nt4) * 16 + c0;
#pragma unroll
    for (int p = 0; p < 2; ++p) {
      unsigned du = cvtpk(fmaxf(u[nt4][2 * p], 0.f), fmaxf(u[nt4][2 * p + 1], 0.f));
      Dh[quad * 4 + 2 * p][col] = (ushortT)(du & 0xFFFFu);
      Dh[quad * 4 + 2 * p + 1][col] = (ushortT)(du >> 16);
      unsigned dv = cvtpk(fmaxf(v[nt4][2 * p], 0.f), fmaxf(v[nt4][2 * p + 1], 0.f));
      Dh[16 + quad * 4 + 2 * p][col] = (ushortT)(dv & 0xFFFFu);
      Dh[16 + quad * 4 + 2 * p + 1][col] = (ushortT)(dv >> 16);
    }
  }
  __syncthreads();

  // ---- phase 4: out = Hid @ fus_W2 + fus_b2 (bf16-hi) ----
  ffrag o[2], q[2];
#pragma unroll
  for (int nt2 = 0; nt2 < 2; ++nt2) {
    float bias = fus_b2[(wv * 2 + nt2) * 16 + c0];
    o[nt2] = ffrag{bias, bias, bias, bias};
    q[nt2] = o[nt2];
  }
#pragma unroll
  for (int kk = 0; kk < 8; ++kk) {
    bfrag dh0 = *(const bfrag*)&Dh[c0][kk * 32 + quad * 8];
    bfrag dh1 = *(const bfrag*)&Dh[16 + c0][kk * 32 + quad * 8];
#pragma unroll
    for (int nt2 = 0; nt2 < 2; ++nt2) {
      bfrag w = *(const bfrag*)(W2p + (((wv * 2 + nt2) * 8 + kk) * 64 + lane) * 8);
      o[nt2] = MFMA(dh0, w, o[nt2]);
      q[nt2] = MFMA(dh1, w, q[nt2]);
    }
  }
#pragma unroll
  for (int nt2 = 0; nt2 < 2; ++nt2) {
    int col = (wv * 2 + nt2) * 16 + c0;
#pragma unroll
    for (int i = 0; i < 4; ++i) {
      int row = quad * 4 + i;
      out[(size_t)(b * 2016 + p0 + row) * 128 + col] = o[nt2][i];
      out[(size_t)(b * 2016 + p0 + 16 + row) * 128 + col] = q[nt2][i];
    }
  }
}

// ---------------------------------------------------------------------------
extern "C" void kernel_launch(void* const* d_in, const int* in_sizes, int n_in,
                              void* d_out, int out_size, void* d_ws, size_t ws_size,
                              hipStream_t stream) {
  const float* x        = (const float*)d_in[0];
  const int*   presence = (const int*)d_in[1];
  const int*   idx_i    = (const int*)d_in[2];
  const int*   idx_j    = (const int*)d_in[3];
  const float* ops_W1   = (const float*)d_in[4];
  const float* ops_b1   = (const float*)d_in[5];
  const float* ops_W2   = (const float*)d_in[6];
  const float* ops_b2   = (const float*)d_in[7];
  const float* pres_W1  = (const float*)d_in[8];
  const float* pres_b1  = (const float*)d_in[9];
  const float* pres_W2  = (const float*)d_in[10];
  const float* pres_b2  = (const float*)d_in[11];
  const float* fus_W1   = (const float*)d_in[12];
  const float* fus_b1   = (const float*)d_in[13];
  const float* fus_W2   = (const float*)d_in[14];
  const float* fus_b2   = (const float*)d_in[15];

  char* ws = (char*)d_ws;
  ushortT* Gp  = (ushortT*)(ws);            // 512*256*2   = 262144 B
  ushortT* W1p = (ushortT*)(ws + 262144);   // 8*4*4*512*2 = 131072 B
  ushortT* W2p = (ushortT*)(ws + 393216);   // 8*8*512*2   =  65536 B
  float*   CB  = (float*)(ws + 458752);     // 4*256*4     =   4096 B

  prologue<<<564, 256, 0, stream>>>(ops_W1, ops_W2, ops_b2, pres_W1, pres_b1,
                                    pres_W2, pres_b2, fus_W1, fus_b1, fus_W2,
                                    Gp, W1p, W2p, CB);
  // 64 batches * 63 blocks, 32 tokens each = 129024 tokens
  drel_main<<<4032, 256, 0, stream>>>(x, presence, idx_i, idx_j, ops_b1, fus_b2,
                                      W1p, Gp, W2p, CB, (float*)d_out);
}